// Round 1
// baseline (328.261 us; speedup 1.0000x reference)
//
#include <hip/hip_runtime.h>

// FM second-order interaction:
//   out[b,k] = (sum_f v[b,f]*E[idx[b,f],k])^2 - sum_f (v[b,f]*E[idx[b,f],k])^2
// B=16384, F=50, K=64, table = 1e6 x 64 fp32 (256 MB ~ L3 size).
// Memory-bound gather: one wave per batch row, lane k = embed dim k.
// Each embedding gather = 64 consecutive floats = one coalesced 256B wave load.

constexpr int BATCH  = 16384;
constexpr int FIELDS = 50;
constexpr int EMBED  = 64;
constexpr int WAVES_PER_BLOCK = 4;   // 256 threads

__global__ __launch_bounds__(256)
void fm_second_order_kernel(const float* __restrict__ vals,   // [B, F]
                            const int*   __restrict__ idx,    // [B, F]
                            const float* __restrict__ emb,    // [1e6, K]
                            float* __restrict__ out)          // [B, K]
{
    const int wave = threadIdx.x >> 6;
    const int lane = threadIdx.x & 63;
    const int b    = blockIdx.x * WAVES_PER_BLOCK + wave;
    if (b >= BATCH) return;

    const float* vrow = vals + (size_t)b * FIELDS;
    const int*   irow = idx  + (size_t)b * FIELDS;

    float acc1 = 0.0f;   // sum of v*e
    float acc2 = 0.0f;   // sum of (v*e)^2

    // Full unroll: lets the compiler issue many independent gathers
    // (global_load_dword) before the first s_waitcnt — latency hiding via MLP.
#pragma unroll
    for (int f = 0; f < FIELDS; ++f) {
        const float v  = vrow[f];          // wave-uniform broadcast
        const int   id = irow[f];          // wave-uniform broadcast
        const float e  = emb[(size_t)id * EMBED + lane];  // coalesced 256B/wave
        const float ve = v * e;
        acc1 += ve;
        acc2 = fmaf(ve, ve, acc2);
    }

    out[(size_t)b * EMBED + lane] = fmaf(acc1, acc1, -acc2);
}

extern "C" void kernel_launch(void* const* d_in, const int* in_sizes, int n_in,
                              void* d_out, int out_size, void* d_ws, size_t ws_size,
                              hipStream_t stream) {
    const float* vals = (const float*)d_in[0];   // feature_values [B,F]
    const int*   idx  = (const int*)d_in[1];     // feature_idx    [B,F]
    const float* emb  = (const float*)d_in[2];   // feature_embeddings [1e6,K]
    float*       out  = (float*)d_out;           // [B,K]

    const int blocks = BATCH / WAVES_PER_BLOCK;  // 4096
    fm_second_order_kernel<<<blocks, WAVES_PER_BLOCK * 64, 0, stream>>>(vals, idx, emb, out);
}

// Round 2
// 326.706 us; speedup vs baseline: 1.0048x; 1.0048x over previous
//
#include <hip/hip_runtime.h>

// FM second-order: out[b,k] = (sum_f v*e)^2 - sum_f (v*e)^2
// B=16384, F=50, K=64, emb table 1e6 x 64 fp32 (256 MB).
//
// v2: float4 gathers. One wave per batch row. lane = 16*g + j:
//   g in [0,4) = field subgroup (field f = 4*it + g)
//   j in [0,16) = k-quad (covers k = 4j .. 4j+3 via float4)
// Each gather instruction moves 64 lanes x 16 B = 1 KB (4 embedding rows),
// 4x fewer vmem instructions than the scalar-lane layout -> more bytes in
// flight per tracked request. Final cross-group reduce: shfl_xor 16, 32.

constexpr int BATCH  = 16384;
constexpr int FIELDS = 50;
constexpr int EMBED  = 64;
constexpr int WAVES_PER_BLOCK = 4;   // 256 threads
constexpr int FITER  = 13;           // ceil(50/4); last iter masked for g>=2

__global__ __launch_bounds__(256)
void fm_second_order_v2(const float* __restrict__ vals,   // [B, F]
                        const int*   __restrict__ idx,    // [B, F]
                        const float* __restrict__ emb,    // [1e6, K]
                        float* __restrict__ out)          // [B, K]
{
    const int wave = threadIdx.x >> 6;
    const int lane = threadIdx.x & 63;
    const int g    = lane >> 4;     // field subgroup
    const int j    = lane & 15;     // k-quad
    const int b    = blockIdx.x * WAVES_PER_BLOCK + wave;

    const float* vrow = vals + (size_t)b * FIELDS;
    const int*   irow = idx  + (size_t)b * FIELDS;

    float4 s1 = make_float4(0.f, 0.f, 0.f, 0.f);  // sum v*e (partial over g's fields)
    float4 s2 = make_float4(0.f, 0.f, 0.f, 0.f);  // sum (v*e)^2

#pragma unroll
    for (int it = 0; it < FITER; ++it) {
        const int  f  = it * 4 + g;
        const bool ok = (f < FIELDS);
        // Per-16-lane-broadcast loads; L1-resident after first touch.
        const float v  = ok ? vrow[f] : 0.0f;
        const int   id = ok ? irow[f] : 0;
        const float4 e = *(const float4*)(emb + (size_t)id * EMBED + j * 4);
        const float vx = v * e.x, vy = v * e.y, vz = v * e.z, vw = v * e.w;
        s1.x += vx; s1.y += vy; s1.z += vz; s1.w += vw;
        s2.x = fmaf(vx, vx, s2.x);
        s2.y = fmaf(vy, vy, s2.y);
        s2.z = fmaf(vz, vz, s2.z);
        s2.w = fmaf(vw, vw, s2.w);
    }

    // Reduce the 4 field-subgroups: lanes {j, j+16, j+32, j+48} hold partials
    // for the same k-quad. Butterfly xor-16 then xor-32.
#pragma unroll
    for (int mask = 16; mask <= 32; mask <<= 1) {
        s1.x += __shfl_xor(s1.x, mask, 64);
        s1.y += __shfl_xor(s1.y, mask, 64);
        s1.z += __shfl_xor(s1.z, mask, 64);
        s1.w += __shfl_xor(s1.w, mask, 64);
        s2.x += __shfl_xor(s2.x, mask, 64);
        s2.y += __shfl_xor(s2.y, mask, 64);
        s2.z += __shfl_xor(s2.z, mask, 64);
        s2.w += __shfl_xor(s2.w, mask, 64);
    }

    if (g == 0) {
        float4 r;
        r.x = fmaf(s1.x, s1.x, -s2.x);
        r.y = fmaf(s1.y, s1.y, -s2.y);
        r.z = fmaf(s1.z, s1.z, -s2.z);
        r.w = fmaf(s1.w, s1.w, -s2.w);
        *(float4*)(out + (size_t)b * EMBED + j * 4) = r;
    }
}

extern "C" void kernel_launch(void* const* d_in, const int* in_sizes, int n_in,
                              void* d_out, int out_size, void* d_ws, size_t ws_size,
                              hipStream_t stream) {
    const float* vals = (const float*)d_in[0];
    const int*   idx  = (const int*)d_in[1];
    const float* emb  = (const float*)d_in[2];
    float*       out  = (float*)d_out;

    const int blocks = BATCH / WAVES_PER_BLOCK;  // 4096
    fm_second_order_v2<<<blocks, WAVES_PER_BLOCK * 64, 0, stream>>>(vals, idx, emb, out);
}